// Round 7
// baseline (1170.641 us; speedup 1.0000x reference)
//
#include <hip/hip_runtime.h>
#include <type_traits>

#define BDIM 8
#define LDIM 2048
#define DDIM 1024
#define NL 3
#define K4 4
#define MDIM (BDIM * LDIM) /* 16384 rows */
#define BK32 32
#define NT32 (DDIM / BK32) /* 32 K-tiles */

typedef __bf16 bf16x8 __attribute__((ext_vector_type(8)));
typedef __bf16 bf16x4 __attribute__((ext_vector_type(4)));
typedef float f32x4 __attribute__((ext_vector_type(4)));
typedef const __attribute__((address_space(1))) void gvoid_t;
typedef __attribute__((address_space(3))) void svoid_t;

// wave-uniform LDS base; lane l's 16B lands at base + l*16 (m104/m108).
__device__ __forceinline__ void load16(const void* g, void* lds_uniform) {
    __builtin_amdgcn_global_load_lds((gvoid_t*)g, (svoid_t*)lds_uniform, 16, 0, 0);
}

#define SBAR()                                  \
    do {                                        \
        asm volatile("" ::: "memory");          \
        __builtin_amdgcn_s_barrier();           \
        asm volatile("" ::: "memory");          \
    } while (0)
#define WAITV(N) asm volatile("s_waitcnt vmcnt(" #N ")" ::: "memory")
#define LGKM0() asm volatile("s_waitcnt lgkmcnt(0)" ::: "memory")
#define SCHED0() __builtin_amdgcn_sched_barrier(0)

__device__ __forceinline__ unsigned lds_addr(const void* p) {
    return (unsigned)(unsigned long long)(svoid_t*)(p);
}
// opaque LDS read (rule #18 pattern): ordering via explicit SBAR/WAITV/LGKM0.
__device__ __forceinline__ bf16x8 dsr16(unsigned a) {
    f32x4 r;
    asm volatile("ds_read_b128 %0, %1" : "=v"(r) : "v"(a));
    return __builtin_bit_cast(bf16x8, r);
}

__global__ void cvt_bf16(const float* __restrict__ s, __bf16* __restrict__ d, int n) {
    int i = blockIdx.x * 256 + threadIdx.x;
    if (i < n) d[i] = (__bf16)s[i];
}

// interleave Wr/Wi rows: W2[l][2d][k] = Wr[l][d][k], W2[l][2d+1][k] = Wi[l][d][k]
__global__ __launch_bounds__(256) void cvt_interleave(const float* __restrict__ wr,
                                                      const float* __restrict__ wi,
                                                      __bf16* __restrict__ w2, int n) {
    int i = blockIdx.x * 256 + threadIdx.x;
    if (i >= n) return;
    int k = i & (DDIM - 1);
    int ld = i >> 10; /* l*D + d */
    int l = ld >> 10;
    int d = ld & (DDIM - 1);
    size_t base = ((size_t)l * 2 * DDIM + 2 * d) * DDIM + k;
    w2[base] = (__bf16)wr[i];
    w2[base + DDIM] = (__bf16)wi[i];
}

// causal depthwise conv1d k=4, left pad 3. X:(B,L,D) -> XC:(B,L,D) bf16
template <typename T>
__global__ __launch_bounds__(256) void conv_kernel(const T* __restrict__ X,
                                                   const float* __restrict__ cw,
                                                   const float* __restrict__ cb,
                                                   __bf16* __restrict__ XC) {
    int idx = blockIdx.x * 256 + threadIdx.x;
    int d = (idx & (DDIM / 4 - 1)) << 2;
    int t = (idx >> 8) & (LDIM - 1);
    int b = idx >> 19;
    float wv[4][4];
    *(float4*)wv[0] = ((const float4*)cw)[d + 0];
    *(float4*)wv[1] = ((const float4*)cw)[d + 1];
    *(float4*)wv[2] = ((const float4*)cw)[d + 2];
    *(float4*)wv[3] = ((const float4*)cw)[d + 3];
    float4 cbv = *(const float4*)(cb + d);
    float acc[4] = {cbv.x, cbv.y, cbv.z, cbv.w};
#pragma unroll
    for (int k = 0; k < K4; k++) {
        int tt = t + k - (K4 - 1);
        if (tt >= 0) {
            size_t off = ((size_t)(b * LDIM + tt) << 10) + d;
            float xv[4];
            if constexpr (std::is_same<T, float>::value) {
                float4 v = *(const float4*)(X + off);
                xv[0] = v.x; xv[1] = v.y; xv[2] = v.z; xv[3] = v.w;
            } else {
                bf16x4 v = *(const bf16x4*)(X + off);
                xv[0] = (float)v.x; xv[1] = (float)v.y; xv[2] = (float)v.z; xv[3] = (float)v.w;
            }
#pragma unroll
            for (int j = 0; j < 4; j++) acc[j] += xv[j] * wv[j][k];
        }
    }
    bf16x4 o;
    o.x = (__bf16)acc[0]; o.y = (__bf16)acc[1]; o.z = (__bf16)acc[2]; o.w = (__bf16)acc[3];
    *(bf16x4*)(XC + ((size_t)(b * LDIM + t) << 10) + d) = o;
}

// ---- 256x256-tile GEMM: BK=32, 4 LDS bufs, depth-3 prefetch, counted vmcnt,
//      register-pipelined fragments: every ds_read batch drains under an MFMA
//      cluster; next tile's B/A0 reads issue right after the per-tile barrier
//      and hide under the current tile's second MFMA cluster (m201 pipeline).
__global__ __launch_bounds__(512, 2) void gate_gemm(
    const __bf16* __restrict__ A, const __bf16* __restrict__ W2,
    const float* __restrict__ wrb, const float* __restrict__ wib,
    const float* __restrict__ la,
    __bf16* __restrict__ LOGA, __bf16* __restrict__ BB) {
    __shared__ __attribute__((aligned(16))) __bf16 sm[65536]; // 128 KiB: 4 bufs x [A 16K|B 16K]
    int tid = threadIdx.x;
    int wave = tid >> 6, lane = tid & 63;
    int wm = wave >> 2, wn = wave & 3; // 2M x 4N waves, each 128x64 out
    int fr = lane & 15, quad = lane >> 4;

    int nx = gridDim.x;
    int bid = blockIdx.y * nx + blockIdx.x;
    int cpx = (nx * gridDim.y) >> 3;
    int sw = (bid & 7) * cpx + (bid >> 3);
    int bm0 = (sw / nx) * 256;
    int bn0 = (sw % nx) * 256; // merged-N origin

    const __bf16* Ag = A + (size_t)bm0 * DDIM;
    const __bf16* Bg = W2 + (size_t)bn0 * DDIM;

    f32x4 acc[8][4];
    f32x4 zero = {0.f, 0.f, 0.f, 0.f};
#pragma unroll
    for (int i = 0; i < 8; i++)
#pragma unroll
        for (int j = 0; j < 4; j++) acc[i][j] = zero;

    // hoisted fragment LDS byte addresses (buffer 0); per-tile add buf*32768
    unsigned smb = lds_addr(sm);
    unsigned adA[2][4], adB[4];
#pragma unroll
    for (int mh = 0; mh < 2; mh++)
#pragma unroll
        for (int mi = 0; mi < 4; mi++) {
            int row = wm * 128 + (mh * 4 + mi) * 16 + fr;
            adA[mh][mi] = smb + 2u * (row * 32 + ((quad ^ ((row >> 1) & 3)) << 3));
        }
#pragma unroll
    for (int ni = 0; ni < 4; ni++) {
        int row = wn * 64 + ni * 16 + fr;
        adB[ni] = smb + 2u * (8192 + row * 32 + ((quad ^ ((row >> 1) & 3)) << 3));
    }
    // staging: pre-swizzled global src, wave-uniform LDS dest
    int r0 = tid >> 2, g0 = (tid & 3) ^ ((r0 >> 1) & 3);
    int r1 = (512 + tid) >> 2, g1 = ((512 + tid) & 3) ^ ((r1 >> 1) & 3);
    const __bf16* gA0 = Ag + (size_t)r0 * DDIM + g0 * 8;
    const __bf16* gA1 = Ag + (size_t)r1 * DDIM + g1 * 8;
    const __bf16* gB0 = Bg + (size_t)r0 * DDIM + g0 * 8;
    const __bf16* gB1 = Bg + (size_t)r1 * DDIM + g1 * 8;
    int lb0 = wave * 512, lb1 = 4096 + wave * 512;

    auto STAGE = [&](int buf, int t) {
        int lo = buf * 16384;
        load16(gA0 + t * BK32, sm + lo + lb0);
        load16(gA1 + t * BK32, sm + lo + lb1);
        load16(gB0 + t * BK32, sm + lo + 8192 + lb0);
        load16(gB1 + t * BK32, sm + lo + 8192 + lb1);
    };

    STAGE(0, 0);
    STAGE(1, 1);
    STAGE(2, 2);
    WAITV(8); // drain tile 0 (t1,t2 stay in flight)
    SBAR();
    // pre-issue tile 0's B + A(mh0) fragments
    bf16x8 bs[2][4], acur[4];
#pragma unroll
    for (int ni = 0; ni < 4; ni++) bs[0][ni] = dsr16(adB[ni]);
#pragma unroll
    for (int mi = 0; mi < 4; mi++) acur[mi] = dsr16(adA[0][mi]);

    for (int t4 = 0; t4 < NT32; t4 += 4) {
#pragma unroll
        for (int u = 0; u < 4; u++) {
            int t = t4 + u;
            unsigned tb = (unsigned)(u * 32768);
            LGKM0();  // B(t), A0(t) ready (drained under t-1's mh1 MFMAs)
            SCHED0();
            bf16x8 af2[4];
#pragma unroll
            for (int mi = 0; mi < 4; mi++) af2[mi] = dsr16(adA[1][mi] + tb);
            __builtin_amdgcn_s_setprio(1);
#pragma unroll
            for (int ni = 0; ni < 4; ni++)
#pragma unroll
                for (int mi = 0; mi < 4; mi++)
                    acc[mi][ni] = __builtin_amdgcn_mfma_f32_16x16x32_bf16(
                        acur[mi], bs[u & 1][ni], acc[mi][ni], 0, 0, 0);
            __builtin_amdgcn_s_setprio(0);
            LGKM0();  // A1(t) ready (drained under mh0 MFMAs)
            SCHED0();
            if (t + 2 < NT32) { WAITV(4); }  // drain t+1's DMA; t+2 in flight
            else { WAITV(0); }
            SBAR();  // t+1 buffer globally visible; buf (t+3)&3 free
            if (t + 3 < NT32) STAGE((u + 3) & 3, t + 3);
            if (t + 1 < NT32) {  // pre-issue next tile's B + A0
                unsigned tb2 = (unsigned)(((u + 1) & 3) * 32768);
#pragma unroll
                for (int ni = 0; ni < 4; ni++) bs[(u + 1) & 1][ni] = dsr16(adB[ni] + tb2);
#pragma unroll
                for (int mi = 0; mi < 4; mi++) acur[mi] = dsr16(adA[0][mi] + tb2);
            }
            __builtin_amdgcn_s_setprio(1);
#pragma unroll
            for (int ni = 0; ni < 4; ni++)
#pragma unroll
                for (int mi = 0; mi < 4; mi++)
                    acc[4 + mi][ni] = __builtin_amdgcn_mfma_f32_16x16x32_bf16(
                        af2[mi], bs[u & 1][ni], acc[4 + mi][ni], 0, 0, 0);
            __builtin_amdgcn_s_setprio(0);
        }
    }

    // ---- gate epilogue: per mi, dump 32x256 f32 slice, re-read transposed ----
    float* Lt = (float*)&sm[0]; // [32][260] f32 = 33.3 KB
    int colg = (tid & 31) * 8;  // 8 merged cols = 4 (r,i) pairs
    int d0 = (bn0 >> 1) + (colg >> 1);
    float rb[4], ibv[4], lnab[4];
    {
        float4 r4 = *(const float4*)(wrb + d0);
        float4 i4 = *(const float4*)(wib + d0);
        float4 l4 = *(const float4*)(la + d0);
        float lav[4] = {l4.x, l4.y, l4.z, l4.w};
        rb[0] = r4.x; rb[1] = r4.y; rb[2] = r4.z; rb[3] = r4.w;
        ibv[0] = i4.x; ibv[1] = i4.y; ibv[2] = i4.z; ibv[3] = i4.w;
#pragma unroll
        for (int j = 0; j < 4; j++) lnab[j] = __logf(1.f / (1.f + __expf(-lav[j])));
    }
#pragma unroll
    for (int mi = 0; mi < 8; mi++) {
        __syncthreads();
#pragma unroll
        for (int ni = 0; ni < 4; ni++) {
            int col = wn * 64 + ni * 16 + fr;
#pragma unroll
            for (int reg = 0; reg < 4; reg++)
                Lt[(wm * 16 + quad * 4 + reg) * 260 + col] = acc[mi][ni][reg];
        }
        __syncthreads();
#pragma unroll
        for (int hf = 0; hf < 2; hf++) {
            int r = (tid >> 5) + hf * 16;
            int m = bm0 + (r >> 4) * 128 + mi * 16 + (r & 15);
            float vv[8];
            *(f32x4*)&vv[0] = *(const f32x4*)&Lt[r * 260 + colg];
            *(f32x4*)&vv[4] = *(const f32x4*)&Lt[r * 260 + colg + 4];
            bf16x4 xcv = *(const bf16x4*)(A + (size_t)m * DDIM + d0);
            bf16x4 og, ob;
#pragma unroll
            for (int j = 0; j < 4; j++) {
                float rv = 1.f / (1.f + __expf(-(vv[2 * j] + rb[j])));
                float iv = 1.f / (1.f + __expf(-(vv[2 * j + 1] + ibv[j])));
                float lga = 8.f * rv * lnab[j];
                float a = __expf(lga);
                float bt = sqrtf(fmaxf(1.f - a * a, 1e-6f)) * (iv * (float)xcv[j]);
                og[j] = (__bf16)lga;
                ob[j] = (__bf16)bt;
            }
            *(bf16x4*)(LOGA + (size_t)m * DDIM + d0) = og;
            *(bf16x4*)(BB + (size_t)m * DDIM + d0) = ob;
        }
    }
}

// HW = A @ Wo^T, same register-pipelined structure, plain transposed epilogue.
__global__ __launch_bounds__(512, 2) void out_gemm(
    const __bf16* __restrict__ A, const __bf16* __restrict__ Wo, __bf16* __restrict__ HW) {
    __shared__ __attribute__((aligned(16))) __bf16 sm[65536]; // 128 KiB
    int tid = threadIdx.x;
    int wave = tid >> 6, lane = tid & 63;
    int wm = wave >> 2, wn = wave & 3;
    int fr = lane & 15, quad = lane >> 4;

    int nx = gridDim.x;
    int bid = blockIdx.y * nx + blockIdx.x;
    int cpx = (nx * gridDim.y) >> 3;
    int sw = (bid & 7) * cpx + (bid >> 3);
    int bm0 = (sw / nx) * 256;
    int bn0 = (sw % nx) * 256;

    const __bf16* Ag = A + (size_t)bm0 * DDIM;
    const __bf16* Bg = Wo + (size_t)bn0 * DDIM;

    f32x4 acc[8][4];
    f32x4 zero = {0.f, 0.f, 0.f, 0.f};
#pragma unroll
    for (int i = 0; i < 8; i++)
#pragma unroll
        for (int j = 0; j < 4; j++) acc[i][j] = zero;

    unsigned smb = lds_addr(sm);
    unsigned adA[2][4], adB[4];
#pragma unroll
    for (int mh = 0; mh < 2; mh++)
#pragma unroll
        for (int mi = 0; mi < 4; mi++) {
            int row = wm * 128 + (mh * 4 + mi) * 16 + fr;
            adA[mh][mi] = smb + 2u * (row * 32 + ((quad ^ ((row >> 1) & 3)) << 3));
        }
#pragma unroll
    for (int ni = 0; ni < 4; ni++) {
        int row = wn * 64 + ni * 16 + fr;
        adB[ni] = smb + 2u * (8192 + row * 32 + ((quad ^ ((row >> 1) & 3)) << 3));
    }
    int r0 = tid >> 2, g0 = (tid & 3) ^ ((r0 >> 1) & 3);
    int r1 = (512 + tid) >> 2, g1 = ((512 + tid) & 3) ^ ((r1 >> 1) & 3);
    const __bf16* gA0 = Ag + (size_t)r0 * DDIM + g0 * 8;
    const __bf16* gA1 = Ag + (size_t)r1 * DDIM + g1 * 8;
    const __bf16* gB0 = Bg + (size_t)r0 * DDIM + g0 * 8;
    const __bf16* gB1 = Bg + (size_t)r1 * DDIM + g1 * 8;
    int lb0 = wave * 512, lb1 = 4096 + wave * 512;

    auto STAGE = [&](int buf, int t) {
        int lo = buf * 16384;
        load16(gA0 + t * BK32, sm + lo + lb0);
        load16(gA1 + t * BK32, sm + lo + lb1);
        load16(gB0 + t * BK32, sm + lo + 8192 + lb0);
        load16(gB1 + t * BK32, sm + lo + 8192 + lb1);
    };

    STAGE(0, 0);
    STAGE(1, 1);
    STAGE(2, 2);
    WAITV(8);
    SBAR();
    bf16x8 bs[2][4], acur[4];
#pragma unroll
    for (int ni = 0; ni < 4; ni++) bs[0][ni] = dsr16(adB[ni]);
#pragma unroll
    for (int mi = 0; mi < 4; mi++) acur[mi] = dsr16(adA[0][mi]);

    for (int t4 = 0; t4 < NT32; t4 += 4) {
#pragma unroll
        for (int u = 0; u < 4; u++) {
            int t = t4 + u;
            unsigned tb = (unsigned)(u * 32768);
            LGKM0();
            SCHED0();
            bf16x8 af2[4];
#pragma unroll
            for (int mi = 0; mi < 4; mi++) af2[mi] = dsr16(adA[1][mi] + tb);
            __builtin_amdgcn_s_setprio(1);
#pragma unroll
            for (int ni = 0; ni < 4; ni++)
#pragma unroll
                for (int mi = 0; mi < 4; mi++)
                    acc[mi][ni] = __builtin_amdgcn_mfma_f32_16x16x32_bf16(
                        acur[mi], bs[u & 1][ni], acc[mi][ni], 0, 0, 0);
            __builtin_amdgcn_s_setprio(0);
            LGKM0();
            SCHED0();
            if (t + 2 < NT32) { WAITV(4); }
            else { WAITV(0); }
            SBAR();
            if (t + 3 < NT32) STAGE((u + 3) & 3, t + 3);
            if (t + 1 < NT32) {
                unsigned tb2 = (unsigned)(((u + 1) & 3) * 32768);
#pragma unroll
                for (int ni = 0; ni < 4; ni++) bs[(u + 1) & 1][ni] = dsr16(adB[ni] + tb2);
#pragma unroll
                for (int mi = 0; mi < 4; mi++) acur[mi] = dsr16(adA[0][mi] + tb2);
            }
            __builtin_amdgcn_s_setprio(1);
#pragma unroll
            for (int ni = 0; ni < 4; ni++)
#pragma unroll
                for (int mi = 0; mi < 4; mi++)
                    acc[4 + mi][ni] = __builtin_amdgcn_mfma_f32_16x16x32_bf16(
                        af2[mi], bs[u & 1][ni], acc[4 + mi][ni], 0, 0, 0);
            __builtin_amdgcn_s_setprio(0);
        }
    }

    float* Lt = (float*)&sm[0]; // [32][260]
    int colg = (tid & 31) * 8;
    int n0 = bn0 + colg;
#pragma unroll
    for (int mi = 0; mi < 8; mi++) {
        __syncthreads();
#pragma unroll
        for (int ni = 0; ni < 4; ni++) {
            int col = wn * 64 + ni * 16 + fr;
#pragma unroll
            for (int reg = 0; reg < 4; reg++)
                Lt[(wm * 16 + quad * 4 + reg) * 260 + col] = acc[mi][ni][reg];
        }
        __syncthreads();
#pragma unroll
        for (int hf = 0; hf < 2; hf++) {
            int r = (tid >> 5) + hf * 16;
            int m = bm0 + (r >> 4) * 128 + mi * 16 + (r & 15);
            float vv[8];
            *(f32x4*)&vv[0] = *(const f32x4*)&Lt[r * 260 + colg];
            *(f32x4*)&vv[4] = *(const f32x4*)&Lt[r * 260 + colg + 4];
            bf16x8 o;
#pragma unroll
            for (int j = 0; j < 8; j++) o[j] = (__bf16)vv[j];
            *(bf16x8*)(HW + (size_t)m * DDIM + n0) = o;
        }
    }
}

// Clamped log-space scan: 32 chunks x 64 steps, 1024-thread blocks (16 waves/CU).
#define SCH 32
#define SCT 64
__global__ __launch_bounds__(1024) void scan_kernel(const __bf16* __restrict__ LOGA,
                                                    const __bf16* __restrict__ BB,
                                                    __bf16* __restrict__ H) {
    int b = blockIdx.y;
    int dl = threadIdx.x & 31;
    int d = blockIdx.x * 32 + dl;
    int c = threadIdx.x >> 5;
    size_t base = ((size_t)b * LDIM + (size_t)c * SCT) * DDIM + d;
    const __bf16* pga = LOGA + base;
    const __bf16* pbb = BB + base;
    __bf16* pH = H + base;

    float S = 0.f;
#pragma unroll 8
    for (int t = 0; t < SCT; t++) S += (float)pga[(size_t)t * DDIM];
    __shared__ float sS[SCH][32];
    sS[c][dl] = S;
    __syncthreads();
    float L0 = 0.f;
    for (int cc = 0; cc < c; cc++) L0 += sS[cc][dl];

    float Lr = L0, lcp = fmaxf(L0, -80.f), hB = 0.f;
#pragma unroll 4
    for (int t = 0; t < SCT; t++) {
        float lga = (float)pga[(size_t)t * DDIM];
        Lr += lga;
        float lc = fmaxf(Lr, -80.f);
        hB = __expf(lc - lcp) * hB + (float)pbb[(size_t)t * DDIM];
        lcp = lc;
    }
    float Ac = __expf(fmaxf(Lr, -80.f) - fmaxf(L0, -80.f));
    __shared__ float sA[SCH][32], sB[SCH][32];
    sA[c][dl] = Ac;
    sB[c][dl] = hB;
    __syncthreads();
    float hin = 0.f;
    for (int cc = 0; cc < c; cc++) hin = sA[cc][dl] * hin + sB[cc][dl];

    Lr = L0;
    lcp = fmaxf(L0, -80.f);
    float h = hin;
#pragma unroll 4
    for (int t = 0; t < SCT; t++) {
        float lga = (float)pga[(size_t)t * DDIM];
        Lr += lga;
        float lc = fmaxf(Lr, -80.f);
        h = __expf(lc - lcp) * h + (float)pbb[(size_t)t * DDIM];
        lcp = lc;
        pH[(size_t)t * DDIM] = (__bf16)h;
    }
}

// rmsnorm over last dim (1024); one block per row, 256 threads x 4 elems.
template <typename TI, typename TO>
__global__ __launch_bounds__(256) void rmsnorm_kernel(const TI* __restrict__ X,
                                                      const float* __restrict__ w,
                                                      TO* __restrict__ Y) {
    int row = blockIdx.x;
    int tid = threadIdx.x;
    size_t off = (size_t)row * DDIM + tid * 4;
    float v[4];
    if constexpr (std::is_same<TI, float>::value) {
        float4 t = *(const float4*)(X + off);
        v[0] = t.x; v[1] = t.y; v[2] = t.z; v[3] = t.w;
    } else {
        bf16x4 t = *(const bf16x4*)(X + off);
        v[0] = (float)t.x; v[1] = (float)t.y; v[2] = (float)t.z; v[3] = (float)t.w;
    }
    float s = v[0] * v[0] + v[1] * v[1] + v[2] * v[2] + v[3] * v[3];
#pragma unroll
    for (int o = 32; o > 0; o >>= 1) s += __shfl_down(s, o);
    __shared__ float sw[4];
    if ((tid & 63) == 0) sw[tid >> 6] = s;
    __syncthreads();
    float tot = sw[0] + sw[1] + sw[2] + sw[3];
    float scale = rsqrtf(tot * (1.f / (float)DDIM) + 1e-6f);
    float4 wv = ((const float4*)w)[tid];
    float o0 = v[0] * wv.x * scale, o1 = v[1] * wv.y * scale;
    float o2 = v[2] * wv.z * scale, o3 = v[3] * wv.w * scale;
    if constexpr (std::is_same<TO, float>::value) {
        float4 o = {o0, o1, o2, o3};
        *(float4*)(Y + off) = o;
    } else {
        bf16x4 o;
        o.x = (__bf16)o0; o.y = (__bf16)o1; o.z = (__bf16)o2; o.w = (__bf16)o3;
        *(bf16x4*)(Y + off) = o;
    }
}

// fused double rmsnorm: Y = rmsnorm(rmsnorm(X, w1), w2), bf16 in, f32 out.
__global__ __launch_bounds__(256) void rmsnorm2_kernel(const __bf16* __restrict__ X,
                                                       const float* __restrict__ w1,
                                                       const float* __restrict__ w2,
                                                       float* __restrict__ Y) {
    int row = blockIdx.x;
    int tid = threadIdx.x;
    size_t off = (size_t)row * DDIM + tid * 4;
    bf16x4 t = *(const bf16x4*)(X + off);
    float v[4] = {(float)t.x, (float)t.y, (float)t.z, (float)t.w};
    float s = v[0] * v[0] + v[1] * v[1] + v[2] * v[2] + v[3] * v[3];
#pragma unroll
    for (int o = 32; o > 0; o >>= 1) s += __shfl_down(s, o);
    __shared__ float sw[8];
    if ((tid & 63) == 0) sw[tid >> 6] = s;
    __syncthreads();
    float scale1 = rsqrtf((sw[0] + sw[1] + sw[2] + sw[3]) * (1.f / (float)DDIM) + 1e-6f);
    float4 w1v = ((const float4*)w1)[tid];
    float y[4] = {v[0] * w1v.x * scale1, v[1] * w1v.y * scale1,
                  v[2] * w1v.z * scale1, v[3] * w1v.w * scale1};
    float s2 = y[0] * y[0] + y[1] * y[1] + y[2] * y[2] + y[3] * y[3];
#pragma unroll
    for (int o = 32; o > 0; o >>= 1) s2 += __shfl_down(s2, o);
    __syncthreads();
    if ((tid & 63) == 0) sw[4 + (tid >> 6)] = s2;
    __syncthreads();
    float scale2 = rsqrtf((sw[4] + sw[5] + sw[6] + sw[7]) * (1.f / (float)DDIM) + 1e-6f);
    float4 w2v = ((const float4*)w2)[tid];
    float4 o = {y[0] * w2v.x * scale2, y[1] * w2v.y * scale2,
                y[2] * w2v.z * scale2, y[3] * w2v.w * scale2};
    *(float4*)(Y + off) = o;
}

extern "C" void kernel_launch(void* const* d_in, const int* in_sizes, int n_in,
                              void* d_out, int out_size, void* d_ws, size_t ws_size,
                              hipStream_t stream) {
    const float* x = (const float*)d_in[0];
    const float* conv_w = (const float*)d_in[1];
    const float* conv_b = (const float*)d_in[2];
    const float* wr_w = (const float*)d_in[3];
    const float* wr_b = (const float*)d_in[4];
    const float* wi_w = (const float*)d_in[5];
    const float* wi_b = (const float*)d_in[6];
    const float* log_a = (const float*)d_in[7];
    const float* wo_w = (const float*)d_in[8];
    const float* norm_w = (const float*)d_in[9];
    const float* norm_out_w = (const float*)d_in[10];

    const size_t W2SZ = (size_t)NL * 2 * DDIM * DDIM; /* interleaved r/i weight */
    const size_t WOSZ = (size_t)NL * DDIM * DDIM;
    const size_t MD = (size_t)MDIM * DDIM;
    __bf16* w2 = (__bf16*)d_ws;
    __bf16* wo16 = w2 + W2SZ;
    __bf16* XC = wo16 + WOSZ;
    __bf16* LGA = XC + MD;
    __bf16* BBf = LGA + MD;
    __bf16* Hb = BBf + MD;
    __bf16* HWb = Hb + MD;
    __bf16* PNb = HWb + MD;

    int nw = (int)WOSZ;
    cvt_interleave<<<(nw + 255) / 256, 256, 0, stream>>>(wr_w, wi_w, w2, nw);
    cvt_bf16<<<(nw + 255) / 256, 256, 0, stream>>>(wo_w, wo16, nw);

    for (int l = 0; l < NL; l++) {
        if (l == 0)
            conv_kernel<float><<<(MDIM * (DDIM / 4)) / 256, 256, 0, stream>>>(
                x, conv_w, conv_b, XC);
        else
            conv_kernel<__bf16><<<(MDIM * (DDIM / 4)) / 256, 256, 0, stream>>>(
                PNb, conv_w + (size_t)l * DDIM * K4, conv_b + (size_t)l * DDIM, XC);
        gate_gemm<<<dim3(2 * DDIM / 256, MDIM / 256), 512, 0, stream>>>(
            XC, w2 + (size_t)l * 2 * DDIM * DDIM,
            wr_b + (size_t)l * DDIM, wi_b + (size_t)l * DDIM, log_a + (size_t)l * DDIM,
            LGA, BBf);
        scan_kernel<<<dim3(DDIM / 32, BDIM), 1024, 0, stream>>>(LGA, BBf, Hb);
        out_gemm<<<dim3(DDIM / 256, MDIM / 256), 512, 0, stream>>>(
            Hb, wo16 + (size_t)l * DDIM * DDIM, HWb);
        if (l < NL - 1)
            rmsnorm_kernel<__bf16, __bf16><<<MDIM, 256, 0, stream>>>(
                HWb, norm_w + (size_t)l * DDIM, PNb);
    }
    // fused: rmsnorm(norm_w[NL-1]) then rmsnorm(norm_out_w) -> f32 out
    rmsnorm2_kernel<<<MDIM, 256, 0, stream>>>(
        HWb, norm_w + (size_t)(NL - 1) * DDIM, norm_out_w, (float*)d_out);
}

// Round 8
// 891.271 us; speedup vs baseline: 1.3135x; 1.3135x over previous
//
#include <hip/hip_runtime.h>
#include <type_traits>

#define BDIM 8
#define LDIM 2048
#define DDIM 1024
#define NL 3
#define K4 4
#define MDIM (BDIM * LDIM) /* 16384 rows */

typedef __bf16 bf16x8 __attribute__((ext_vector_type(8)));
typedef __bf16 bf16x4 __attribute__((ext_vector_type(4)));
typedef float f32x4 __attribute__((ext_vector_type(4)));
typedef const __attribute__((address_space(1))) void gvoid_t;
typedef __attribute__((address_space(3))) void svoid_t;

// wave-uniform LDS base; lane l's 16B lands at base + l*16 (m104/m108).
__device__ __forceinline__ void load16(const void* g, void* lds_uniform) {
    __builtin_amdgcn_global_load_lds((gvoid_t*)g, (svoid_t*)lds_uniform, 16, 0, 0);
}

__global__ void cvt_bf16(const float* __restrict__ s, __bf16* __restrict__ d, int n) {
    int i = blockIdx.x * 256 + threadIdx.x;
    if (i < n) d[i] = (__bf16)s[i];
}

// interleave Wr/Wi rows: W2[l][2d][k] = Wr[l][d][k], W2[l][2d+1][k] = Wi[l][d][k]
__global__ __launch_bounds__(256) void cvt_interleave(const float* __restrict__ wr,
                                                      const float* __restrict__ wi,
                                                      __bf16* __restrict__ w2, int n) {
    int i = blockIdx.x * 256 + threadIdx.x;
    if (i >= n) return;
    int k = i & (DDIM - 1);
    int ld = i >> 10; /* l*D + d */
    int l = ld >> 10;
    int d = ld & (DDIM - 1);
    size_t base = ((size_t)l * 2 * DDIM + 2 * d) * DDIM + k;
    w2[base] = (__bf16)wr[i];
    w2[base + DDIM] = (__bf16)wi[i];
}

// causal depthwise conv1d k=4, left pad 3. X:(B,L,D) -> XC:(B,L,D) bf16
template <typename T>
__global__ __launch_bounds__(256) void conv_kernel(const T* __restrict__ X,
                                                   const float* __restrict__ cw,
                                                   const float* __restrict__ cb,
                                                   __bf16* __restrict__ XC) {
    int idx = blockIdx.x * 256 + threadIdx.x;
    int d = (idx & (DDIM / 4 - 1)) << 2;
    int t = (idx >> 8) & (LDIM - 1);
    int b = idx >> 19;
    float wv[4][4];
    *(float4*)wv[0] = ((const float4*)cw)[d + 0];
    *(float4*)wv[1] = ((const float4*)cw)[d + 1];
    *(float4*)wv[2] = ((const float4*)cw)[d + 2];
    *(float4*)wv[3] = ((const float4*)cw)[d + 3];
    float4 cbv = *(const float4*)(cb + d);
    float acc[4] = {cbv.x, cbv.y, cbv.z, cbv.w};
#pragma unroll
    for (int k = 0; k < K4; k++) {
        int tt = t + k - (K4 - 1);
        if (tt >= 0) {
            size_t off = ((size_t)(b * LDIM + tt) << 10) + d;
            float xv[4];
            if constexpr (std::is_same<T, float>::value) {
                float4 v = *(const float4*)(X + off);
                xv[0] = v.x; xv[1] = v.y; xv[2] = v.z; xv[3] = v.w;
            } else {
                bf16x4 v = *(const bf16x4*)(X + off);
                xv[0] = (float)v.x; xv[1] = (float)v.y; xv[2] = (float)v.z; xv[3] = (float)v.w;
            }
#pragma unroll
            for (int j = 0; j < 4; j++) acc[j] += xv[j] * wv[j][k];
        }
    }
    bf16x4 o;
    o.x = (__bf16)acc[0]; o.y = (__bf16)acc[1]; o.z = (__bf16)acc[2]; o.w = (__bf16)acc[3];
    *(bf16x4*)(XC + ((size_t)(b * LDIM + t) << 10) + d) = o;
}

// ---- 128x128-tile GEMM, m97 structure: BK=64, single 32KB LDS buffer,
//      2-barrier K-loop, plain C++ reads, 3 blocks/CU for antiphase overlap.
//      LDS[r][sc] holds global chunk sc^(r&7) (chunk = 8 bf16 = 16B).
__global__ __launch_bounds__(256, 3) void gate_gemm(
    const __bf16* __restrict__ A, const __bf16* __restrict__ W2,
    const float* __restrict__ wrb, const float* __restrict__ wib,
    const float* __restrict__ la,
    __bf16* __restrict__ LOGA, __bf16* __restrict__ BB) {
    __shared__ __attribute__((aligned(16))) __bf16 sm[16384]; // 32 KiB: A 8192 | B 8192
    int tid = threadIdx.x;
    int wave = tid >> 6, lane = tid & 63;
    int wm = wave >> 1, wn = wave & 1; // 2x2 waves, each 64x64 out
    int fr = lane & 15, quad = lane >> 4;

    // T1: bijective XCD swizzle (nwg % 8 == 0)
    int nx = gridDim.x;
    int bid = blockIdx.y * nx + blockIdx.x;
    int cpx = (nx * gridDim.y) >> 3;
    int sw = (bid & 7) * cpx + (bid >> 3);
    int bm0 = (sw / nx) * 128;
    int bn0 = (sw % nx) * 128; // merged-N origin

    const __bf16* Ag = A + (size_t)bm0 * DDIM;
    const __bf16* Bg = W2 + (size_t)bn0 * DDIM;

    f32x4 acc[4][4];
    f32x4 zero = {0.f, 0.f, 0.f, 0.f};
#pragma unroll
    for (int i = 0; i < 4; i++)
#pragma unroll
        for (int j = 0; j < 4; j++) acc[i][j] = zero;

    // hoisted staging: 4 chunks/thread per matrix, pre-swizzled global src
    const __bf16* gAs[4];
    const __bf16* gBs[4];
    int ub[4];
#pragma unroll
    for (int j = 0; j < 4; j++) {
        int ci = j * 256 + tid;
        int r = ci >> 3, sc = ci & 7;
        int g = sc ^ (r & 7);
        gAs[j] = Ag + (size_t)r * DDIM + g * 8;
        gBs[j] = Bg + (size_t)r * DDIM + g * 8;
        ub[j] = (j * 256 + wave * 64) * 8; // wave-uniform element base
    }

    for (int ko = 0; ko < DDIM; ko += 64) {
        if (ko) __syncthreads();
#pragma unroll
        for (int j = 0; j < 4; j++) {
            load16(gAs[j] + ko, sm + ub[j]);
            load16(gBs[j] + ko, sm + 8192 + ub[j]);
        }
        __syncthreads();
#pragma unroll
        for (int kw = 0; kw < 2; kw++) {
            bf16x8 af[4], bf[4];
#pragma unroll
            for (int mi = 0; mi < 4; mi++) {
                int row = wm * 64 + mi * 16 + fr;
                af[mi] = *(const bf16x8*)(sm + row * 64 + (((kw * 4 + quad) ^ (row & 7)) << 3));
            }
#pragma unroll
            for (int ni = 0; ni < 4; ni++) {
                int row = wn * 64 + ni * 16 + fr;
                bf[ni] = *(const bf16x8*)(sm + 8192 + row * 64 + (((kw * 4 + quad) ^ (row & 7)) << 3));
            }
#pragma unroll
            for (int ni = 0; ni < 4; ni++)
#pragma unroll
                for (int mi = 0; mi < 4; mi++)
                    acc[mi][ni] = __builtin_amdgcn_mfma_f32_16x16x32_bf16(
                        af[mi], bf[ni], acc[mi][ni], 0, 0, 0);
        }
    }

    // ---- gate epilogue: per mi, dump 32x128 f32 slice, re-read transposed ----
    float* Lt = (float*)&sm[0]; // [32][132] f32 = 16.9 KB
    int wrow = (wave >> 1) * 16, wcol = (wave & 1) * 64;
    int colg = (tid & 15) * 8; // 8 merged cols = 4 (r,i) pairs
    int d0 = (bn0 >> 1) + (colg >> 1);
    float rb[4], ibv[4], lnab[4];
    {
        float4 r4 = *(const float4*)(wrb + d0);
        float4 i4 = *(const float4*)(wib + d0);
        float4 l4 = *(const float4*)(la + d0);
        float lav[4] = {l4.x, l4.y, l4.z, l4.w};
        rb[0] = r4.x; rb[1] = r4.y; rb[2] = r4.z; rb[3] = r4.w;
        ibv[0] = i4.x; ibv[1] = i4.y; ibv[2] = i4.z; ibv[3] = i4.w;
#pragma unroll
        for (int j = 0; j < 4; j++) lnab[j] = __logf(1.f / (1.f + __expf(-lav[j])));
    }
#pragma unroll
    for (int mi = 0; mi < 4; mi++) {
        __syncthreads();
#pragma unroll
        for (int ni = 0; ni < 4; ni++) {
            int col = wcol + ni * 16 + fr;
#pragma unroll
            for (int reg = 0; reg < 4; reg++)
                Lt[(wrow + quad * 4 + reg) * 132 + col] = acc[mi][ni][reg];
        }
        __syncthreads();
#pragma unroll
        for (int hf = 0; hf < 2; hf++) {
            int lrow = (tid >> 4) + hf * 16;
            int m = bm0 + (lrow >> 4) * 64 + mi * 16 + (lrow & 15);
            float vv[8];
            *(f32x4*)&vv[0] = *(const f32x4*)&Lt[lrow * 132 + colg];
            *(f32x4*)&vv[4] = *(const f32x4*)&Lt[lrow * 132 + colg + 4];
            bf16x4 xcv = *(const bf16x4*)(A + (size_t)m * DDIM + d0);
            bf16x4 og, ob;
#pragma unroll
            for (int j = 0; j < 4; j++) {
                float rv = 1.f / (1.f + __expf(-(vv[2 * j] + rb[j])));
                float iv = 1.f / (1.f + __expf(-(vv[2 * j + 1] + ibv[j])));
                float lga = 8.f * rv * lnab[j];
                float a = __expf(lga);
                float bt = sqrtf(fmaxf(1.f - a * a, 1e-6f)) * (iv * (float)xcv[j]);
                og[j] = (__bf16)lga;
                ob[j] = (__bf16)bt;
            }
            *(bf16x4*)(LOGA + (size_t)m * DDIM + d0) = og;
            *(bf16x4*)(BB + (size_t)m * DDIM + d0) = ob;
        }
    }
}

// HW = A @ Wo^T, same m97 128-tile structure, plain transposed epilogue.
__global__ __launch_bounds__(256, 3) void out_gemm(
    const __bf16* __restrict__ A, const __bf16* __restrict__ Wo, __bf16* __restrict__ HW) {
    __shared__ __attribute__((aligned(16))) __bf16 sm[16384]; // 32 KiB
    int tid = threadIdx.x;
    int wave = tid >> 6, lane = tid & 63;
    int wm = wave >> 1, wn = wave & 1;
    int fr = lane & 15, quad = lane >> 4;

    int nx = gridDim.x;
    int bid = blockIdx.y * nx + blockIdx.x;
    int cpx = (nx * gridDim.y) >> 3;
    int sw = (bid & 7) * cpx + (bid >> 3);
    int bm0 = (sw / nx) * 128;
    int bn0 = (sw % nx) * 128;

    const __bf16* Ag = A + (size_t)bm0 * DDIM;
    const __bf16* Bg = Wo + (size_t)bn0 * DDIM;

    f32x4 acc[4][4];
    f32x4 zero = {0.f, 0.f, 0.f, 0.f};
#pragma unroll
    for (int i = 0; i < 4; i++)
#pragma unroll
        for (int j = 0; j < 4; j++) acc[i][j] = zero;

    const __bf16* gAs[4];
    const __bf16* gBs[4];
    int ub[4];
#pragma unroll
    for (int j = 0; j < 4; j++) {
        int ci = j * 256 + tid;
        int r = ci >> 3, sc = ci & 7;
        int g = sc ^ (r & 7);
        gAs[j] = Ag + (size_t)r * DDIM + g * 8;
        gBs[j] = Bg + (size_t)r * DDIM + g * 8;
        ub[j] = (j * 256 + wave * 64) * 8;
    }

    for (int ko = 0; ko < DDIM; ko += 64) {
        if (ko) __syncthreads();
#pragma unroll
        for (int j = 0; j < 4; j++) {
            load16(gAs[j] + ko, sm + ub[j]);
            load16(gBs[j] + ko, sm + 8192 + ub[j]);
        }
        __syncthreads();
#pragma unroll
        for (int kw = 0; kw < 2; kw++) {
            bf16x8 af[4], bf[4];
#pragma unroll
            for (int mi = 0; mi < 4; mi++) {
                int row = wm * 64 + mi * 16 + fr;
                af[mi] = *(const bf16x8*)(sm + row * 64 + (((kw * 4 + quad) ^ (row & 7)) << 3));
            }
#pragma unroll
            for (int ni = 0; ni < 4; ni++) {
                int row = wn * 64 + ni * 16 + fr;
                bf[ni] = *(const bf16x8*)(sm + 8192 + row * 64 + (((kw * 4 + quad) ^ (row & 7)) << 3));
            }
#pragma unroll
            for (int ni = 0; ni < 4; ni++)
#pragma unroll
                for (int mi = 0; mi < 4; mi++)
                    acc[mi][ni] = __builtin_amdgcn_mfma_f32_16x16x32_bf16(
                        af[mi], bf[ni], acc[mi][ni], 0, 0, 0);
        }
    }

    float* Lt = (float*)&sm[0]; // [32][132]
    int wrow = (wave >> 1) * 16, wcol = (wave & 1) * 64;
    int colg = (tid & 15) * 8;
    int n0 = bn0 + colg;
#pragma unroll
    for (int mi = 0; mi < 4; mi++) {
        __syncthreads();
#pragma unroll
        for (int ni = 0; ni < 4; ni++) {
            int col = wcol + ni * 16 + fr;
#pragma unroll
            for (int reg = 0; reg < 4; reg++)
                Lt[(wrow + quad * 4 + reg) * 132 + col] = acc[mi][ni][reg];
        }
        __syncthreads();
#pragma unroll
        for (int hf = 0; hf < 2; hf++) {
            int lrow = (tid >> 4) + hf * 16;
            int m = bm0 + (lrow >> 4) * 64 + mi * 16 + (lrow & 15);
            float vv[8];
            *(f32x4*)&vv[0] = *(const f32x4*)&Lt[lrow * 132 + colg];
            *(f32x4*)&vv[4] = *(const f32x4*)&Lt[lrow * 132 + colg + 4];
            bf16x8 o;
#pragma unroll
            for (int j = 0; j < 8; j++) o[j] = (__bf16)vv[j];
            *(bf16x8*)(HW + (size_t)m * DDIM + n0) = o;
        }
    }
}

// Clamped log-space scan: 32 chunks x 64 steps, 1024-thread blocks (16 waves/CU).
#define SCH 32
#define SCT 64
__global__ __launch_bounds__(1024) void scan_kernel(const __bf16* __restrict__ LOGA,
                                                    const __bf16* __restrict__ BB,
                                                    __bf16* __restrict__ H) {
    int b = blockIdx.y;
    int dl = threadIdx.x & 31;
    int d = blockIdx.x * 32 + dl;
    int c = threadIdx.x >> 5;
    size_t base = ((size_t)b * LDIM + (size_t)c * SCT) * DDIM + d;
    const __bf16* pga = LOGA + base;
    const __bf16* pbb = BB + base;
    __bf16* pH = H + base;

    float S = 0.f;
#pragma unroll 8
    for (int t = 0; t < SCT; t++) S += (float)pga[(size_t)t * DDIM];
    __shared__ float sS[SCH][32];
    sS[c][dl] = S;
    __syncthreads();
    float L0 = 0.f;
    for (int cc = 0; cc < c; cc++) L0 += sS[cc][dl];

    float Lr = L0, lcp = fmaxf(L0, -80.f), hB = 0.f;
#pragma unroll 4
    for (int t = 0; t < SCT; t++) {
        float lga = (float)pga[(size_t)t * DDIM];
        Lr += lga;
        float lc = fmaxf(Lr, -80.f);
        hB = __expf(lc - lcp) * hB + (float)pbb[(size_t)t * DDIM];
        lcp = lc;
    }
    float Ac = __expf(fmaxf(Lr, -80.f) - fmaxf(L0, -80.f));
    __shared__ float sA[SCH][32], sB[SCH][32];
    sA[c][dl] = Ac;
    sB[c][dl] = hB;
    __syncthreads();
    float hin = 0.f;
    for (int cc = 0; cc < c; cc++) hin = sA[cc][dl] * hin + sB[cc][dl];

    Lr = L0;
    lcp = fmaxf(L0, -80.f);
    float h = hin;
#pragma unroll 4
    for (int t = 0; t < SCT; t++) {
        float lga = (float)pga[(size_t)t * DDIM];
        Lr += lga;
        float lc = fmaxf(Lr, -80.f);
        h = __expf(lc - lcp) * h + (float)pbb[(size_t)t * DDIM];
        lcp = lc;
        pH[(size_t)t * DDIM] = (__bf16)h;
    }
}

// rmsnorm over last dim (1024); one block per row, 256 threads x 4 elems.
template <typename TI, typename TO>
__global__ __launch_bounds__(256) void rmsnorm_kernel(const TI* __restrict__ X,
                                                      const float* __restrict__ w,
                                                      TO* __restrict__ Y) {
    int row = blockIdx.x;
    int tid = threadIdx.x;
    size_t off = (size_t)row * DDIM + tid * 4;
    float v[4];
    if constexpr (std::is_same<TI, float>::value) {
        float4 t = *(const float4*)(X + off);
        v[0] = t.x; v[1] = t.y; v[2] = t.z; v[3] = t.w;
    } else {
        bf16x4 t = *(const bf16x4*)(X + off);
        v[0] = (float)t.x; v[1] = (float)t.y; v[2] = (float)t.z; v[3] = (float)t.w;
    }
    float s = v[0] * v[0] + v[1] * v[1] + v[2] * v[2] + v[3] * v[3];
#pragma unroll
    for (int o = 32; o > 0; o >>= 1) s += __shfl_down(s, o);
    __shared__ float sw[4];
    if ((tid & 63) == 0) sw[tid >> 6] = s;
    __syncthreads();
    float tot = sw[0] + sw[1] + sw[2] + sw[3];
    float scale = rsqrtf(tot * (1.f / (float)DDIM) + 1e-6f);
    float4 wv = ((const float4*)w)[tid];
    float o0 = v[0] * wv.x * scale, o1 = v[1] * wv.y * scale;
    float o2 = v[2] * wv.z * scale, o3 = v[3] * wv.w * scale;
    if constexpr (std::is_same<TO, float>::value) {
        float4 o = {o0, o1, o2, o3};
        *(float4*)(Y + off) = o;
    } else {
        bf16x4 o;
        o.x = (__bf16)o0; o.y = (__bf16)o1; o.z = (__bf16)o2; o.w = (__bf16)o3;
        *(bf16x4*)(Y + off) = o;
    }
}

// fused double rmsnorm: Y = rmsnorm(rmsnorm(X, w1), w2), bf16 in, f32 out.
__global__ __launch_bounds__(256) void rmsnorm2_kernel(const __bf16* __restrict__ X,
                                                       const float* __restrict__ w1,
                                                       const float* __restrict__ w2,
                                                       float* __restrict__ Y) {
    int row = blockIdx.x;
    int tid = threadIdx.x;
    size_t off = (size_t)row * DDIM + tid * 4;
    bf16x4 t = *(const bf16x4*)(X + off);
    float v[4] = {(float)t.x, (float)t.y, (float)t.z, (float)t.w};
    float s = v[0] * v[0] + v[1] * v[1] + v[2] * v[2] + v[3] * v[3];
#pragma unroll
    for (int o = 32; o > 0; o >>= 1) s += __shfl_down(s, o);
    __shared__ float sw[8];
    if ((tid & 63) == 0) sw[tid >> 6] = s;
    __syncthreads();
    float scale1 = rsqrtf((sw[0] + sw[1] + sw[2] + sw[3]) * (1.f / (float)DDIM) + 1e-6f);
    float4 w1v = ((const float4*)w1)[tid];
    float y[4] = {v[0] * w1v.x * scale1, v[1] * w1v.y * scale1,
                  v[2] * w1v.z * scale1, v[3] * w1v.w * scale1};
    float s2 = y[0] * y[0] + y[1] * y[1] + y[2] * y[2] + y[3] * y[3];
#pragma unroll
    for (int o = 32; o > 0; o >>= 1) s2 += __shfl_down(s2, o);
    __syncthreads();
    if ((tid & 63) == 0) sw[4 + (tid >> 6)] = s2;
    __syncthreads();
    float scale2 = rsqrtf((sw[4] + sw[5] + sw[6] + sw[7]) * (1.f / (float)DDIM) + 1e-6f);
    float4 w2v = ((const float4*)w2)[tid];
    float4 o = {y[0] * w2v.x * scale2, y[1] * w2v.y * scale2,
                y[2] * w2v.z * scale2, y[3] * w2v.w * scale2};
    *(float4*)(Y + off) = o;
}

extern "C" void kernel_launch(void* const* d_in, const int* in_sizes, int n_in,
                              void* d_out, int out_size, void* d_ws, size_t ws_size,
                              hipStream_t stream) {
    const float* x = (const float*)d_in[0];
    const float* conv_w = (const float*)d_in[1];
    const float* conv_b = (const float*)d_in[2];
    const float* wr_w = (const float*)d_in[3];
    const float* wr_b = (const float*)d_in[4];
    const float* wi_w = (const float*)d_in[5];
    const float* wi_b = (const float*)d_in[6];
    const float* log_a = (const float*)d_in[7];
    const float* wo_w = (const float*)d_in[8];
    const float* norm_w = (const float*)d_in[9];
    const float* norm_out_w = (const float*)d_in[10];

    const size_t W2SZ = (size_t)NL * 2 * DDIM * DDIM; /* interleaved r/i weight */
    const size_t WOSZ = (size_t)NL * DDIM * DDIM;
    const size_t MD = (size_t)MDIM * DDIM;
    __bf16* w2 = (__bf16*)d_ws;
    __bf16* wo16 = w2 + W2SZ;
    __bf16* XC = wo16 + WOSZ;
    __bf16* LGA = XC + MD;
    __bf16* BBf = LGA + MD;
    __bf16* Hb = BBf + MD;
    __bf16* HWb = Hb + MD;
    __bf16* PNb = HWb + MD;

    int nw = (int)WOSZ;
    cvt_interleave<<<(nw + 255) / 256, 256, 0, stream>>>(wr_w, wi_w, w2, nw);
    cvt_bf16<<<(nw + 255) / 256, 256, 0, stream>>>(wo_w, wo16, nw);

    for (int l = 0; l < NL; l++) {
        if (l == 0)
            conv_kernel<float><<<(MDIM * (DDIM / 4)) / 256, 256, 0, stream>>>(
                x, conv_w, conv_b, XC);
        else
            conv_kernel<__bf16><<<(MDIM * (DDIM / 4)) / 256, 256, 0, stream>>>(
                PNb, conv_w + (size_t)l * DDIM * K4, conv_b + (size_t)l * DDIM, XC);
        gate_gemm<<<dim3(2 * DDIM / 128, MDIM / 128), 256, 0, stream>>>(
            XC, w2 + (size_t)l * 2 * DDIM * DDIM,
            wr_b + (size_t)l * DDIM, wi_b + (size_t)l * DDIM, log_a + (size_t)l * DDIM,
            LGA, BBf);
        scan_kernel<<<dim3(DDIM / 32, BDIM), 1024, 0, stream>>>(LGA, BBf, Hb);
        out_gemm<<<dim3(DDIM / 128, MDIM / 128), 256, 0, stream>>>(
            Hb, wo16 + (size_t)l * DDIM * DDIM, HWb);
        if (l < NL - 1)
            rmsnorm_kernel<__bf16, __bf16><<<MDIM, 256, 0, stream>>>(
                HWb, norm_w + (size_t)l * DDIM, PNb);
    }
    // fused: rmsnorm(norm_w[NL-1]) then rmsnorm(norm_out_w) -> f32 out
    rmsnorm2_kernel<<<MDIM, 256, 0, stream>>>(
        HWb, norm_w + (size_t)(NL - 1) * DDIM, norm_out_w, (float*)d_out);
}